// Round 1
// baseline (751.203 us; speedup 1.0000x reference)
//
#include <hip/hip_runtime.h>
#include <hip/hip_bf16.h>

#define N_TOK 4096
#define DIM   1024
#define VOCAB 32000
#define BM 128
#define BN 128
#define BK 32
#define SMOOTH 0.1f

typedef __attribute__((ext_vector_type(8))) short short8v;
typedef __attribute__((ext_vector_type(4))) float float4v;

__device__ __forceinline__ unsigned short f2bf(float f) {
  union { float f; unsigned u; } c; c.f = f;
  unsigned r = c.u + 0x7fffu + ((c.u >> 16) & 1u);
  return (unsigned short)(r >> 16);
}

// f32 -> bf16 (RNE), 4 elems/thread, coalesced float4 in / 8B out
__global__ void cvt_bf16(const float* __restrict__ src, unsigned short* __restrict__ dst, int n4) {
  int i = blockIdx.x * blockDim.x + threadIdx.x;
  if (i >= n4) return;
  float4 v = ((const float4*)src)[i];
  unsigned long long p = (unsigned long long)f2bf(v.x)
                       | ((unsigned long long)f2bf(v.y) << 16)
                       | ((unsigned long long)f2bf(v.z) << 32)
                       | ((unsigned long long)f2bf(v.w) << 48);
  ((unsigned long long*)dst)[i] = p;
}

__device__ __forceinline__ void gload_lds16(const unsigned short* g, unsigned short* l) {
  __builtin_amdgcn_global_load_lds((const __attribute__((address_space(1))) unsigned int*)g,
                                   (__attribute__((address_space(3))) unsigned int*)l,
                                   16, 0, 0);
}

// C = Xb[4096,1024] * Wb[32000,1024]^T, fused CE-stat epilogue.
// 128x128 tile, 4 waves in 2x2, each wave 4x4 MFMAs of 16x16x32 bf16.
__global__ __launch_bounds__(256)
void gemm_ce(const unsigned short* __restrict__ Xb, const unsigned short* __restrict__ Wb,
             const int* __restrict__ y,
             float* __restrict__ rowExp, float* __restrict__ rowSum, float* __restrict__ tgtSum) {
  __shared__ __align__(16) unsigned short As[BM * BK];  // 8 KB, row-major [128][32], no pad (global_load_lds)
  __shared__ __align__(16) unsigned short Bs[BN * BK];  // 8 KB
  __shared__ int ys[BM];

  const int jb = blockIdx.x;   // vocab tile (250)
  const int ib = blockIdx.y;   // token tile (32)
  const int row0 = ib * BM;
  const int col0 = jb * BN;

  const int tid  = threadIdx.x;
  const int wv   = tid >> 6;
  const int lane = tid & 63;
  const int wr = wv >> 1, wc = wv & 1;     // wave quadrant in 2x2
  const int quad = lane >> 4;
  const int r16  = lane & 15;

  if (tid < BM) ys[tid] = y[row0 + tid];

  float4v acc[4][4];
#pragma unroll
  for (int i = 0; i < 4; ++i)
#pragma unroll
    for (int j = 0; j < 4; ++j) acc[i][j] = (float4v){0.f, 0.f, 0.f, 0.f};

  const int lrow = lane >> 2;        // 0..15: row within 16-row stage slab
  const int lcol = (lane & 3) * 8;   // 0,8,16,24: k-offset (8 bf16 = 16B)

  for (int kk = 0; kk < DIM; kk += BK) {
    __syncthreads();   // previous tile's ds_reads done before overwrite
#pragma unroll
    for (int c = 0; c < 2; ++c) {
      const int rA = c * 64 + wv * 16;   // wave-uniform 16-row slab base
      gload_lds16(Xb + (size_t)(row0 + rA + lrow) * DIM + kk + lcol, &As[rA * BK]);
      gload_lds16(Wb + (size_t)(col0 + rA + lrow) * DIM + kk + lcol, &Bs[rA * BK]);
    }
    __syncthreads();   // drains vmcnt(0): staging visible

    short8v af[4], bf[4];
#pragma unroll
    for (int i = 0; i < 4; ++i)
      af[i] = *(const short8v*)&As[(wr * 64 + i * 16 + r16) * BK + quad * 8];
#pragma unroll
    for (int j = 0; j < 4; ++j)
      bf[j] = *(const short8v*)&Bs[(wc * 64 + j * 16 + r16) * BK + quad * 8];
#pragma unroll
    for (int i = 0; i < 4; ++i)
#pragma unroll
      for (int j = 0; j < 4; ++j)
        acc[i][j] = __builtin_amdgcn_mfma_f32_16x16x32_bf16(af[i], bf[j], acc[i][j], 0, 0, 0);
  }

  // Fused epilogue: per-row sum(exp(logit)), sum(logit), target pick.
  // C/D layout: col = r16, row = quad*4 + reg  (within each 16x16 tile)
#pragma unroll
  for (int i = 0; i < 4; ++i) {
#pragma unroll
    for (int r = 0; r < 4; ++r) {
      const int rloc = wr * 64 + i * 16 + quad * 4 + r;
      const int yt = ys[rloc];
      float se = 0.f, ss = 0.f;
#pragma unroll
      for (int j = 0; j < 4; ++j) {
        const float v = acc[i][j][r];
        ss += v;
        se += __expf(v);
        if (col0 + wc * 64 + j * 16 + r16 == yt) atomicAdd(tgtSum, v);  // rare: 4096 hits grid-wide
      }
      // reduce across the 16 lanes (same quad) sharing this row
#pragma unroll
      for (int off = 1; off < 16; off <<= 1) {
        se += __shfl_xor(se, off, 64);
        ss += __shfl_xor(ss, off, 64);
      }
      if (r16 == 0) {
        atomicAdd(&rowExp[row0 + rloc], se);
        atomicAdd(&rowSum[row0 + rloc], ss);
      }
    }
  }
}

// loss = (1/N) sum lse - (1-s)/N * tgt - s/(N*V) * sum(all logits)
__global__ void finalize_kernel(const float* __restrict__ rowExp, const float* __restrict__ rowSum,
                                const float* __restrict__ tgt, float* __restrict__ out) {
  __shared__ float s1[256], s2[256];
  const int t = threadIdx.x;
  float a = 0.f, b = 0.f;
  for (int n = t; n < N_TOK; n += 256) { a += logf(rowExp[n]); b += rowSum[n]; }
  s1[t] = a; s2[t] = b;
  __syncthreads();
  for (int o = 128; o > 0; o >>= 1) {
    if (t < o) { s1[t] += s1[t + o]; s2[t] += s2[t + o]; }
    __syncthreads();
  }
  if (t == 0) {
    const float inviN = 1.0f / (float)N_TOK;
    const float loss = s1[0] * inviN
                     - (1.0f - SMOOTH) * tgt[0] * inviN
                     - SMOOTH * s2[0] / ((float)N_TOK * (float)VOCAB);
    out[0] = loss;
  }
}

extern "C" void kernel_launch(void* const* d_in, const int* in_sizes, int n_in,
                              void* d_out, int out_size, void* d_ws, size_t ws_size,
                              hipStream_t stream) {
  const float* x = (const float*)d_in[0];
  const float* W = (const float*)d_in[1];
  const int*   y = (const int*)d_in[2];
  float* out = (float*)d_out;

  char* ws = (char*)d_ws;
  float* rowExp = (float*)(ws);              // 4096 f32
  float* rowSum = (float*)(ws + 16384);      // 4096 f32
  float* tgt    = (float*)(ws + 32768);      // 1 f32
  unsigned short* Xb = (unsigned short*)(ws + 65536);                            // 8.4 MB
  unsigned short* Wb = (unsigned short*)(ws + 65536 + (size_t)N_TOK * DIM * 2);  // 65.5 MB

  // ws is poisoned 0xAA before every launch: zero the accumulators
  hipMemsetAsync(ws, 0, 33024, stream);

  cvt_bf16<<<(N_TOK * DIM / 4 + 255) / 256, 256, 0, stream>>>(x, Xb, N_TOK * DIM / 4);
  cvt_bf16<<<(VOCAB * DIM / 4 + 255) / 256, 256, 0, stream>>>(W, Wb, VOCAB * DIM / 4);

  dim3 grid(VOCAB / BN, N_TOK / BM);  // (250, 32)
  gemm_ce<<<grid, 256, 0, stream>>>(Xb, Wb, y, rowExp, rowSum, tgt);

  finalize_kernel<<<1, 256, 0, stream>>>(rowExp, rowSum, tgt, out);
}